// Round 1
// baseline (10645.076 us; speedup 1.0000x reference)
//
#include <hip/hip_runtime.h>
#include <math.h>

#define Bn 16
#define Dm 28
#define HWc (28*28)          // 784
#define Sv (28*28*28)        // 21952
#define CNT ((float)(Bn*Sv)) // 351232
#define EPS 1e-5f

// ---------------------------------------------------------------- offsets conv
// x:(16,1,28,28,28)  w:(81,1,3,3,3)  b:(81)  -> out:(16,81,28,28,28)
__global__ __launch_bounds__(256) void k_offsets(const float* __restrict__ x,
        const float* __restrict__ ow, const float* __restrict__ ob,
        float* __restrict__ out) {
    __shared__ float w_s[81 * 27];
    __shared__ float b_s[81];
    for (int i = threadIdx.x; i < 81 * 27; i += 256) w_s[i] = ow[i];
    if (threadIdx.x < 81) b_s[threadIdx.x] = ob[threadIdx.x];
    __syncthreads();
    int idx = blockIdx.x * 256 + threadIdx.x;        // exactly 16*21952 threads
    int n = idx / Sv, s = idx % Sv;
    int d = s / HWc, r = s % HWc, h = r / 28, w = r % 28;
    const float* xb = x + (long)n * Sv;
    float xv[27];
    #pragma unroll
    for (int dz = 0; dz < 3; dz++)
      #pragma unroll
      for (int dy = 0; dy < 3; dy++)
        #pragma unroll
        for (int dx = 0; dx < 3; dx++) {
            int zz = d + dz - 1, yy = h + dy - 1, xx = w + dx - 1;
            bool ok = (unsigned)zz < 28u && (unsigned)yy < 28u && (unsigned)xx < 28u;
            xv[dz * 9 + dy * 3 + dx] = ok ? xb[zz * HWc + yy * 28 + xx] : 0.f;
        }
    float* op = out + (long)n * 81 * Sv + s;
    for (int c = 0; c < 81; c++) {
        float acc = b_s[c];
        #pragma unroll
        for (int k = 0; k < 27; k++) acc += xv[k] * w_s[c * 27 + k];
        op[(long)c * Sv] = acc;
    }
}

// ---------------------------------------------------------------- deform conv
__device__ __forceinline__ float fetch_pad(const float* __restrict__ xb,
                                           int zq, int yq, int xq) {
    int z = zq - 1, y = yq - 1, xx = xq - 1;   // padded coord -> raw coord
    bool ok = (unsigned)z < 28u && (unsigned)y < 28u && (unsigned)xx < 28u;
    return ok ? xb[z * HWc + y * 28 + xx] : 0.f;
}

// x:(16,1,28^3) off:(16,81,28^3) dw:(32,1,27) -> h1 = relu(deform) (16,32,28^3)
__global__ __launch_bounds__(256) void k_deform(const float* __restrict__ x,
        const float* __restrict__ off, const float* __restrict__ dw,
        float* __restrict__ h1) {
    __shared__ float w_s[32 * 27];
    for (int i = threadIdx.x; i < 32 * 27; i += 256) w_s[i] = dw[i];
    __syncthreads();
    int idx = blockIdx.x * 256 + threadIdx.x;
    int n = idx / Sv, s = idx % Sv;
    int d = s / HWc, r = s % HWc, h = r / 28, w = r % 28;
    const float* xb = x + (long)n * Sv;
    const float* ofb = off + (long)n * 81 * Sv + s;
    float v[27];
    #pragma unroll
    for (int k = 0; k < 27; k++) {
        int ki = k / 9, kj = (k / 3) % 3, kl = k % 3;
        float pd = (float)(d + ki) + ofb[(long)k * Sv];          // d+1 + (ki-1)
        float ph = (float)(h + kj) + ofb[(long)(27 + k) * Sv];
        float pw = (float)(w + kl) + ofb[(long)(54 + k) * Sv];
        float q0d = floorf(pd), q0h = floorf(ph), q0w = floorf(pw);
        float pcd = fminf(fmaxf(pd, 0.f), 29.f);
        float pch = fminf(fmaxf(ph, 0.f), 29.f);
        float pcw = fminf(fmaxf(pw, 0.f), 29.f);
        float q0cd = fminf(fmaxf(q0d, 0.f), 29.f);
        float q0ch = fminf(fmaxf(q0h, 0.f), 29.f);
        float q0cw = fminf(fmaxf(q0w, 0.f), 29.f);
        float q1cd = fminf(fmaxf(q0d + 1.f, 0.f), 29.f);
        float q1ch = fminf(fmaxf(q0h + 1.f, 0.f), 29.f);
        float q1cw = fminf(fmaxf(q0w + 1.f, 0.f), 29.f);
        float wz[2] = {1.f + (q0cd - pcd), 1.f - (q1cd - pcd)};
        float wy[2] = {1.f + (q0ch - pch), 1.f - (q1ch - pch)};
        float wx[2] = {1.f + (q0cw - pcw), 1.f - (q1cw - pcw)};
        int qz[2] = {(int)q0cd, (int)q1cd};
        int qy[2] = {(int)q0ch, (int)q1ch};
        int qx[2] = {(int)q0cw, (int)q1cw};
        float val = 0.f;
        #pragma unroll
        for (int cz = 0; cz < 2; cz++)
          #pragma unroll
          for (int cy = 0; cy < 2; cy++)
            #pragma unroll
            for (int cx = 0; cx < 2; cx++)
                val += wz[cz] * wy[cy] * wx[cx] * fetch_pad(xb, qz[cz], qy[cy], qx[cx]);
        v[k] = val;
    }
    float* hb = h1 + (long)n * 32 * Sv + s;
    for (int o = 0; o < 32; o++) {
        float acc = 0.f;
        #pragma unroll
        for (int k = 0; k < 27; k++) acc += v[k] * w_s[o * 27 + k];
        hb[(long)o * Sv] = fmaxf(acc, 0.f);
    }
}

// ------------------------------------------------------- per-channel sum/sumsq
// buf:(B,C,Sv) -> sums[c], sums[C+c].  grid = (8, C)
__global__ __launch_bounds__(256) void k_stats(const float* __restrict__ buf,
        float* __restrict__ sums, int C) {
    int c = blockIdx.y;
    int n0 = blockIdx.x * 2;
    float s1 = 0.f, s2 = 0.f;
    for (int n = n0; n < n0 + 2; n++) {
        const float* p = buf + ((long)n * C + c) * Sv;
        for (int s = threadIdx.x; s < Sv; s += 256) { float v = p[s]; s1 += v; s2 += v * v; }
    }
    __shared__ float r1[256], r2[256];
    int tid = threadIdx.x;
    r1[tid] = s1; r2[tid] = s2;
    __syncthreads();
    for (int o = 128; o; o >>= 1) {
        if (tid < o) { r1[tid] += r1[tid + o]; r2[tid] += r2[tid + o]; }
        __syncthreads();
    }
    if (tid == 0) { atomicAdd(&sums[c], r1[0]); atomicAdd(&sums[C + c], r2[0]); }
}

// stats -> per-channel affine a, b'  (bn(v) = v*a + b')
__global__ void k_finalize(const float* __restrict__ sums, const float* __restrict__ g,
        const float* __restrict__ bb, float* __restrict__ aff, int C) {
    int c = threadIdx.x;
    if (c < C) {
        float mean = sums[c] * (1.f / CNT);
        float var = sums[C + c] * (1.f / CNT) - mean * mean;
        float a = g[c] * rsqrtf(var + EPS);
        aff[c] = a;
        aff[C + c] = bb[c] - mean * a;
    }
}

// ------------------------------------------------------------------ conv3d 3x3x3
// in:(B,CI,Sv) raw (pre-BN); affine[2*CI] applied at staging; bias+relu epilogue.
// STORE: write (B,CO,Sv).  !STORE: reduce -> pooled[n*CO+co] (+= sum v),
//                                          chsumsq[co]      (+= sum v^2)
template<int CI, int CO, bool STORE>
__global__ __launch_bounds__(256) void k_conv(const float* __restrict__ in,
        const float* __restrict__ affine, const float* __restrict__ wgt,
        const float* __restrict__ bias, float* __restrict__ out,
        float* __restrict__ pooled, float* __restrict__ chsumsq) {
    constexpr int CI_T = 16;
    __shared__ float tile[CI_T * 360];   // [ci][dz:3][hy:4][wx:30] = 23 KB
    int bx = blockIdx.x;
    int n = bx / (28 * 14);
    int rem = bx % (28 * 14);
    int d = rem / 14;
    int h0 = (rem % 14) * 2;
    int tid = threadIdx.x;
    int co_l = tid >> 3;
    int slot = tid & 7;
    int row = slot >> 2;              // 0..1
    int wb = (slot & 3) * 7;          // 0,7,14,21
    int co = blockIdx.y * 32 + co_l;
    float acc[7] = {0.f, 0.f, 0.f, 0.f, 0.f, 0.f, 0.f};
    const float* wco = wgt + (long)co * CI * 27;

    for (int ci0 = 0; ci0 < CI; ci0 += CI_T) {
        __syncthreads();
        for (int e = tid; e < CI_T * 360; e += 256) {
            int ci_l = e / 360;
            int rr = e % 360;
            int dz = rr / 120;
            int r2 = rr % 120;
            int hy = r2 / 30;
            int wx = r2 % 30;
            int ci = ci0 + ci_l;
            int zz = d - 1 + dz, yy = h0 - 1 + hy, xx = wx - 1;
            float val = 0.f;
            if ((unsigned)zz < 28u && (unsigned)yy < 28u && (unsigned)xx < 28u)
                val = in[((long)n * CI + ci) * Sv + zz * HWc + yy * 28 + xx]
                      * affine[ci] + affine[CI + ci];
            tile[e] = val;
        }
        __syncthreads();
        for (int ci_l = 0; ci_l < CI_T; ci_l++) {
            const float* wci = wco + (long)(ci0 + ci_l) * 27;
            const float* tci = tile + ci_l * 360;
            #pragma unroll
            for (int dz = 0; dz < 3; dz++) {
                #pragma unroll
                for (int ky = 0; ky < 3; ky++) {
                    const float* trow = tci + dz * 120 + (row + ky) * 30 + wb;
                    float m[9];
                    #pragma unroll
                    for (int q = 0; q < 9; q++) m[q] = trow[q];
                    #pragma unroll
                    for (int kx = 0; kx < 3; kx++) {
                        float wv = wci[dz * 9 + ky * 3 + kx];
                        #pragma unroll
                        for (int i = 0; i < 7; i++) acc[i] += m[kx + i] * wv;
                    }
                }
            }
        }
    }
    float b = bias[co];
    float vs[7];
    #pragma unroll
    for (int i = 0; i < 7; i++) vs[i] = fmaxf(acc[i] + b, 0.f);
    if (STORE) {
        float* ob = out + ((long)n * CO + co) * Sv + d * HWc + (h0 + row) * 28 + wb;
        #pragma unroll
        for (int i = 0; i < 7; i++) ob[i] = vs[i];
    } else {
        float s1 = 0.f, s2 = 0.f;
        #pragma unroll
        for (int i = 0; i < 7; i++) { s1 += vs[i]; s2 += vs[i] * vs[i]; }
        __syncthreads();                    // tile reuse as reduction scratch
        float* r1 = tile; float* r2 = tile + 256;
        r1[tid] = s1; r2[tid] = s2;
        __syncthreads();
        if (slot == 0) {
            float t1 = 0.f, t2 = 0.f;
            for (int j = 0; j < 8; j++) { t1 += r1[co_l * 8 + j]; t2 += r2[co_l * 8 + j]; }
            atomicAdd(&pooled[n * CO + co], t1);
            atomicAdd(&chsumsq[co], t2);
        }
    }
}

// -------------------------------------------------------------------- head
__global__ __launch_bounds__(256) void k_head(const float* __restrict__ pooled,
        const float* __restrict__ chsq, const float* __restrict__ g4,
        const float* __restrict__ b4, const float* __restrict__ fcw,
        const float* __restrict__ fcb, float* __restrict__ out) {
    __shared__ float feat[16 * 128];
    __shared__ float lg[160];
    __shared__ float corr[16];
    int t = threadIdx.x;
    if (t < 128) {
        float sum = 0.f;
        for (int n = 0; n < 16; n++) sum += pooled[n * 128 + t];
        float mean = sum * (1.f / CNT);
        float var = chsq[t] * (1.f / CNT) - mean * mean;
        float a = g4[t] * rsqrtf(var + EPS);
        float bb = b4[t] - mean * a;
        for (int n = 0; n < 16; n++)
            feat[n * 128 + t] = a * (pooled[n * 128 + t] * (1.f / (float)Sv)) + bb;
    }
    __syncthreads();
    if (t < 160) {
        int n = t / 10, j = t % 10;
        float acc = fcb[j];
        for (int c = 0; c < 128; c++) acc += feat[n * 128 + c] * fcw[j * 128 + c];
        lg[t] = acc;
    }
    __syncthreads();
    if (t < 16) {
        float mx = -1e30f;
        for (int j = 0; j < 10; j++) mx = fmaxf(mx, lg[t * 10 + j]);
        float se = 0.f;
        for (int j = 0; j < 10; j++) se += expf(lg[t * 10 + j] - mx);
        corr[t] = mx + logf(se);
    }
    __syncthreads();
    if (t < 160) out[t] = lg[t] - corr[t / 10];
}

// -------------------------------------------------------------------- launch
extern "C" void kernel_launch(void* const* d_in, const int* in_sizes, int n_in,
                              void* d_out, int out_size, void* d_ws, size_t ws_size,
                              hipStream_t stream) {
    const float* x       = (const float*)d_in[0];
    const float* off_w   = (const float*)d_in[1];
    const float* off_b   = (const float*)d_in[2];
    const float* dconv_w = (const float*)d_in[3];
    const float* bn1_g   = (const float*)d_in[4];
    const float* bn1_b   = (const float*)d_in[5];
    const float* conv2_w = (const float*)d_in[6];
    const float* conv2_b = (const float*)d_in[7];
    const float* bn2_g   = (const float*)d_in[8];
    const float* bn2_b   = (const float*)d_in[9];
    const float* conv3_w = (const float*)d_in[10];
    const float* conv3_b = (const float*)d_in[11];
    const float* bn3_g   = (const float*)d_in[12];
    const float* bn3_b   = (const float*)d_in[13];
    const float* conv4_w = (const float*)d_in[14];
    const float* conv4_b = (const float*)d_in[15];
    const float* bn4_g   = (const float*)d_in[16];
    const float* bn4_b   = (const float*)d_in[17];
    const float* fc_w    = (const float*)d_in[18];
    const float* fc_b    = (const float*)d_in[19];

    float* out = (float*)d_out;
    float* offsets = out + 160;                       // second output, in-place

    // workspace layout (bytes):
    //   [0, 179830784)            h3 (16x128xSv f32); h1 (16x32xSv) also lives
    //                             at offset 0 and is dead before h3 is written
    //   [179830784, 269746176)    h2 (16x64xSv f32)
    //   [269746176, +12KB)        stats
    char* ws = (char*)d_ws;
    float* h1 = (float*)ws;
    float* h3 = (float*)ws;
    float* h2 = (float*)(ws + 179830784L);
    float* stats = (float*)(ws + 269746176L);
    float* sums1 = stats;        float* aff1 = stats + 64;
    float* sums2 = stats + 128;  float* aff2 = stats + 256;
    float* sums3 = stats + 384;  float* aff3 = stats + 640;
    float* chsq4 = stats + 896;  float* pooled = stats + 1024;   // [16*128]

    hipMemsetAsync(stats, 0, 3072 * sizeof(float), stream);

    k_offsets<<<dim3(Bn * Sv / 256), 256, 0, stream>>>(x, off_w, off_b, offsets);
    k_deform<<<dim3(Bn * Sv / 256), 256, 0, stream>>>(x, offsets, dconv_w, h1);

    k_stats<<<dim3(8, 32), 256, 0, stream>>>(h1, sums1, 32);
    k_finalize<<<1, 32, 0, stream>>>(sums1, bn1_g, bn1_b, aff1, 32);
    k_conv<32, 64, true><<<dim3(16 * 28 * 14, 2), 256, 0, stream>>>(
        h1, aff1, conv2_w, conv2_b, h2, nullptr, nullptr);

    k_stats<<<dim3(8, 64), 256, 0, stream>>>(h2, sums2, 64);
    k_finalize<<<1, 64, 0, stream>>>(sums2, bn2_g, bn2_b, aff2, 64);
    k_conv<64, 128, true><<<dim3(16 * 28 * 14, 4), 256, 0, stream>>>(
        h2, aff2, conv3_w, conv3_b, h3, nullptr, nullptr);

    k_stats<<<dim3(8, 128), 256, 0, stream>>>(h3, sums3, 128);
    k_finalize<<<1, 128, 0, stream>>>(sums3, bn3_g, bn3_b, aff3, 128);
    k_conv<128, 128, false><<<dim3(16 * 28 * 14, 4), 256, 0, stream>>>(
        h3, aff3, conv4_w, conv4_b, nullptr, pooled, chsq4);

    k_head<<<1, 256, 0, stream>>>(pooled, chsq4, bn4_g, bn4_b, fc_w, fc_b, out);
}

// Round 2
// 2460.224 us; speedup vs baseline: 4.3269x; 4.3269x over previous
//
#include <hip/hip_runtime.h>
#include <math.h>

#define Sv 21952
#define HWc 784
#define CNT 351232.0f
#define EPS 1e-5f
#define PV 27000              // 30^3 padded volume per image
#define PT (16 * PV)          // padded positions total

typedef short bf16x8 __attribute__((ext_vector_type(8)));
typedef float f32x4 __attribute__((ext_vector_type(4)));
typedef unsigned short u16x8 __attribute__((ext_vector_type(8)));

__device__ __forceinline__ unsigned short f2bf(float f) {
    unsigned u = __float_as_uint(f);
    u = (u + 0x7FFFu + ((u >> 16) & 1u)) >> 16;
    return (unsigned short)u;
}
__device__ __forceinline__ float bf2f(unsigned short h) {
    return __uint_as_float(((unsigned)h) << 16);
}

// ---------------------------------------------------------------- offsets conv
// x:(16,1,28^3) w:(81,27) b:(81) -> out:(16,81,28^3) f32 NCDHW (exact, = output 1)
__global__ __launch_bounds__(256) void k_offsets(const float* __restrict__ x,
        const float* __restrict__ ow, const float* __restrict__ ob,
        float* __restrict__ out) {
    __shared__ float w_s[81 * 27];
    __shared__ float b_s[81];
    for (int i = threadIdx.x; i < 81 * 27; i += 256) w_s[i] = ow[i];
    if (threadIdx.x < 81) b_s[threadIdx.x] = ob[threadIdx.x];
    __syncthreads();
    int idx = blockIdx.x * 256 + threadIdx.x;
    int n = idx / Sv, s = idx % Sv;
    int d = s / HWc, r = s % HWc, h = r / 28, w = r % 28;
    const float* xb = x + (long)n * Sv;
    float xv[27];
    #pragma unroll
    for (int dz = 0; dz < 3; dz++)
      #pragma unroll
      for (int dy = 0; dy < 3; dy++)
        #pragma unroll
        for (int dx = 0; dx < 3; dx++) {
            int zz = d + dz - 1, yy = h + dy - 1, xx = w + dx - 1;
            bool ok = (unsigned)zz < 28u && (unsigned)yy < 28u && (unsigned)xx < 28u;
            xv[dz * 9 + dy * 3 + dx] = ok ? xb[zz * HWc + yy * 28 + xx] : 0.f;
        }
    float* op = out + (long)n * 81 * Sv + s;
    for (int c = 0; c < 81; c++) {
        float acc = b_s[c];
        #pragma unroll
        for (int k = 0; k < 27; k++) acc += xv[k] * w_s[c * 27 + k];
        op[(long)c * Sv] = acc;
    }
}

// ---------------------------------------------------------------- deform conv
__device__ __forceinline__ float fetch_pad(const float* __restrict__ xb,
                                           int zq, int yq, int xq) {
    int z = zq - 1, y = yq - 1, xx = xq - 1;
    bool ok = (unsigned)z < 28u && (unsigned)y < 28u && (unsigned)xx < 28u;
    return ok ? xb[z * HWc + y * 28 + xx] : 0.f;
}

// -> h1p: padded NDHWC bf16 (16,30,30,30,32), raw relu(deform)
__global__ __launch_bounds__(256) void k_deform(const float* __restrict__ x,
        const float* __restrict__ off, const float* __restrict__ dw,
        unsigned short* __restrict__ h1p) {
    __shared__ float w_s[32 * 27];
    for (int i = threadIdx.x; i < 32 * 27; i += 256) w_s[i] = dw[i];
    __syncthreads();
    int idx = blockIdx.x * 256 + threadIdx.x;
    int n = idx / Sv, s = idx % Sv;
    int d = s / HWc, r = s % HWc, h = r / 28, w = r % 28;
    const float* xb = x + (long)n * Sv;
    const float* ofb = off + (long)n * 81 * Sv + s;
    float v[27];
    #pragma unroll
    for (int k = 0; k < 27; k++) {
        int ki = k / 9, kj = (k / 3) % 3, kl = k % 3;
        float pd = (float)(d + ki) + ofb[(long)k * Sv];
        float ph = (float)(h + kj) + ofb[(long)(27 + k) * Sv];
        float pw = (float)(w + kl) + ofb[(long)(54 + k) * Sv];
        float q0d = floorf(pd), q0h = floorf(ph), q0w = floorf(pw);
        float pcd = fminf(fmaxf(pd, 0.f), 29.f);
        float pch = fminf(fmaxf(ph, 0.f), 29.f);
        float pcw = fminf(fmaxf(pw, 0.f), 29.f);
        float q0cd = fminf(fmaxf(q0d, 0.f), 29.f);
        float q0ch = fminf(fmaxf(q0h, 0.f), 29.f);
        float q0cw = fminf(fmaxf(q0w, 0.f), 29.f);
        float q1cd = fminf(fmaxf(q0d + 1.f, 0.f), 29.f);
        float q1ch = fminf(fmaxf(q0h + 1.f, 0.f), 29.f);
        float q1cw = fminf(fmaxf(q0w + 1.f, 0.f), 29.f);
        float wz[2] = {1.f + (q0cd - pcd), 1.f - (q1cd - pcd)};
        float wy[2] = {1.f + (q0ch - pch), 1.f - (q1ch - pch)};
        float wx[2] = {1.f + (q0cw - pcw), 1.f - (q1cw - pcw)};
        int qz[2] = {(int)q0cd, (int)q1cd};
        int qy[2] = {(int)q0ch, (int)q1ch};
        int qx[2] = {(int)q0cw, (int)q1cw};
        float val = 0.f;
        #pragma unroll
        for (int cz = 0; cz < 2; cz++)
          #pragma unroll
          for (int cy = 0; cy < 2; cy++)
            #pragma unroll
            for (int cx = 0; cx < 2; cx++)
                val += wz[cz] * wy[cy] * wx[cx] * fetch_pad(xb, qz[cz], qy[cy], qx[cx]);
        v[k] = val;
    }
    unsigned pb = ((((unsigned)n * 30 + (d + 1)) * 30 + (h + 1)) * 30 + (w + 1)) * 32;
    unsigned short tmp[32];
    #pragma unroll
    for (int o = 0; o < 32; o++) {
        float acc = 0.f;
        #pragma unroll
        for (int k = 0; k < 27; k++) acc += v[k] * w_s[o * 27 + k];
        tmp[o] = f2bf(fmaxf(acc, 0.f));
    }
    u16x8* dst = (u16x8*)(h1p + pb);
    #pragma unroll
    for (int q = 0; q < 4; q++) dst[q] = ((u16x8*)tmp)[q];
}

// ------------------------------------------------- BN stats over padded buffer
// halo elements are exactly 0 -> contribute nothing; divide by CNT later.
template<int C>
__global__ __launch_bounds__(256) void k_stats_p(const unsigned short* __restrict__ buf,
        float* __restrict__ sums) {
    constexpr int G = C / 8;
    constexpr int P = 256 / G;
    int t = threadIdx.x;
    int oct = t % G, ps = t / G;
    float s1[8], s2[8];
    #pragma unroll
    for (int j = 0; j < 8; j++) { s1[j] = 0.f; s2[j] = 0.f; }
    for (int p = blockIdx.x * P + ps; p < PT; p += gridDim.x * P) {
        u16x8 v = *(const u16x8*)(buf + (long)p * C + oct * 8);
        #pragma unroll
        for (int j = 0; j < 8; j++) {
            float f = bf2f(v[j]);
            s1[j] += f; s2[j] += f * f;
        }
    }
    __shared__ float sh[2][C];
    if (t < C) { sh[0][t] = 0.f; sh[1][t] = 0.f; }
    __syncthreads();
    #pragma unroll
    for (int j = 0; j < 8; j++) {
        atomicAdd(&sh[0][oct * 8 + j], s1[j]);
        atomicAdd(&sh[1][oct * 8 + j], s2[j]);
    }
    __syncthreads();
    if (t < C) { atomicAdd(&sums[t], sh[0][t]); atomicAdd(&sums[C + t], sh[1][t]); }
}

// stats -> affine: bn(v) = v*aff[c] + aff[C+c]
__global__ void k_finalize(const float* __restrict__ sums, const float* __restrict__ g,
        const float* __restrict__ bb, float* __restrict__ aff, int C) {
    int c = threadIdx.x;
    if (c < C) {
        float mean = sums[c] * (1.f / CNT);
        float var = sums[C + c] * (1.f / CNT) - mean * mean;
        float a = g[c] * rsqrtf(var + EPS);
        aff[c] = a;
        aff[C + c] = bb[c] - mean * a;
    }
}

// ---------------------------------------------- weight prep: B-fragment swizzle
// wf[tap][kc][gnt][lane][8] = bf16( w[co][ci][tap] * aff_a[ci] )
//   co = gnt*16 + (lane&15), ci = kc*32 + (lane>>4)*8 + j
template<int CI, int COT>
__global__ __launch_bounds__(256) void k_wfrag(const float* __restrict__ w,
        const float* __restrict__ affa, unsigned short* __restrict__ wf) {
    int tid = blockIdx.x * 256 + threadIdx.x;
    int lane = tid & 63, rest = tid >> 6;
    int gnt = rest % (COT / 16); rest /= (COT / 16);
    int kc = rest % (CI / 32);
    int tap = rest / (CI / 32);
    if (tap >= 27) return;
    int co = gnt * 16 + (lane & 15);
    unsigned short tmp[8];
    #pragma unroll
    for (int j = 0; j < 8; j++) {
        int ci = kc * 32 + (lane >> 4) * 8 + j;
        tmp[j] = f2bf(w[((long)co * CI + ci) * 27 + tap] * affa[ci]);
    }
    *(u16x8*)(wf + (long)tid * 8) = *(u16x8*)tmp;
}

// border-class bias table: T[cls][co] = bias + sum over valid taps of sum_ci w*affb
template<int CI, int COT>
__global__ void k_btab(const float* __restrict__ w, const float* __restrict__ bias,
        const float* __restrict__ affb, float* __restrict__ T) {
    int tid = blockIdx.x * 256 + threadIdx.x;
    if (tid >= 27 * COT) return;
    int co = tid % COT, cls = tid / COT;
    int xc = cls % 3, yc = (cls / 3) % 3, zc = cls / 9;
    float val = bias[co];
    for (int t = 0; t < 27; t++) {
        int dx = t % 3, dy = (t / 3) % 3, dz = t / 9;
        bool ok = (zc == 1 || (zc == 0 && dz >= 1) || (zc == 2 && dz <= 1))
               && (yc == 1 || (yc == 0 && dy >= 1) || (yc == 2 && dy <= 1))
               && (xc == 1 || (xc == 0 && dx >= 1) || (xc == 2 && dx <= 1));
        if (ok) {
            float s = 0.f;
            for (int ci = 0; ci < CI; ci++) s += w[((long)co * CI + ci) * 27 + t] * affb[ci];
            val += s;
        }
    }
    T[cls * COT + co] = val;
}

// ------------------------------------------------------ MFMA implicit-GEMM conv
// in: padded NDHWC bf16 (CI ch).  out: PAD_OUT ? padded NDHWC (COT ch)
//                                        : unpadded (M,COT) bf16
// grid: (1372, COT/64). wg = 4 waves; wave tile 64(M) x 64(N).
template<int CI, int COT, bool PAD_OUT>
__global__ __launch_bounds__(256) void k_conv_mfma(
        const unsigned short* __restrict__ in,
        const unsigned short* __restrict__ wfrag,
        const float* __restrict__ Ttab,
        unsigned short* __restrict__ out) {
    constexpr int KC = CI / 32;
    constexpr int NTT = COT / 16;
    int tid = threadIdx.x, wv = tid >> 6, lane = tid & 63;
    int lrow = lane & 15, quad = lane >> 4;
    int n0 = blockIdx.y * 64;
    int gnt0 = n0 >> 4;
    int m0 = blockIdx.x * 256 + wv * 64;

    int voffA[4];
    #pragma unroll
    for (int mt = 0; mt < 4; mt++) {
        int s = m0 + mt * 16 + lrow;
        int n = s / Sv, r = s % Sv;
        int z = r / HWc, r2 = r % HWc, y = r2 / 28, xx = r2 % 28;
        voffA[mt] = (((n * 30 + z) * 30 + y) * 30 + xx) * CI + quad * 8;
    }

    f32x4 acc[4][4];
    #pragma unroll
    for (int mt = 0; mt < 4; mt++)
        #pragma unroll
        for (int nt = 0; nt < 4; nt++)
            #pragma unroll
            for (int e = 0; e < 4; e++) acc[mt][nt][e] = 0.f;

    for (int tap = 0; tap < 27; tap++) {
        int dz = tap / 9, dy = (tap / 3) % 3, dx = tap % 3;
        int toff = (dz * 900 + dy * 30 + dx) * CI;
        #pragma unroll
        for (int kc = 0; kc < KC; kc++) {
            const unsigned short* pin = in + toff + kc * 32;
            bf16x8 a[4], b[4];
            #pragma unroll
            for (int mt = 0; mt < 4; mt++)
                a[mt] = *(const bf16x8*)(pin + voffA[mt]);
            const unsigned short* pw =
                wfrag + (long)((tap * KC + kc) * NTT + gnt0) * 512 + lane * 8;
            #pragma unroll
            for (int nt = 0; nt < 4; nt++)
                b[nt] = *(const bf16x8*)(pw + nt * 512);
            #pragma unroll
            for (int mt = 0; mt < 4; mt++)
                #pragma unroll
                for (int nt = 0; nt < 4; nt++)
                    acc[mt][nt] = __builtin_amdgcn_mfma_f32_16x16x32_bf16(
                        a[mt], b[nt], acc[mt][nt], 0, 0, 0);
        }
    }

    #pragma unroll
    for (int mt = 0; mt < 4; mt++) {
        #pragma unroll
        for (int r = 0; r < 4; r++) {
            int s = m0 + mt * 16 + quad * 4 + r;
            int n = s / Sv, rr = s % Sv;
            int z = rr / HWc, r2 = rr % HWc, y = r2 / 28, xx = r2 % 28;
            int zc = (z == 0) ? 0 : ((z == 27) ? 2 : 1);
            int yc = (y == 0) ? 0 : ((y == 27) ? 2 : 1);
            int xc = (xx == 0) ? 0 : ((xx == 27) ? 2 : 1);
            int cls = (zc * 3 + yc) * 3 + xc;
            long ob;
            if (PAD_OUT)
                ob = (long)((((n * 30 + z + 1) * 30 + y + 1) * 30 + xx + 1)) * COT;
            else
                ob = (long)s * COT;
            #pragma unroll
            for (int nt = 0; nt < 4; nt++) {
                int co = n0 + nt * 16 + lrow;
                float v = acc[mt][nt][r] + Ttab[cls * COT + co];
                out[ob + co] = f2bf(fmaxf(v, 0.f));
            }
        }
    }
}

// ------------------------------------------- conv4 pooled/sumsq (h4 unpadded)
__global__ __launch_bounds__(256) void k_stats4(const unsigned short* __restrict__ h4,
        float* __restrict__ pooled, float* __restrict__ chsq) {
    int n = blockIdx.x, zs = blockIdx.y;
    int t = threadIdx.x;
    int oct = t % 16, ps = t / 16;
    long base = (long)n * Sv + zs * HWc;
    float s1[8], s2[8];
    #pragma unroll
    for (int j = 0; j < 8; j++) { s1[j] = 0.f; s2[j] = 0.f; }
    for (int p = ps; p < HWc; p += 16) {
        u16x8 v = *(const u16x8*)(h4 + (base + p) * 128 + oct * 8);
        #pragma unroll
        for (int j = 0; j < 8; j++) {
            float f = bf2f(v[j]);
            s1[j] += f; s2[j] += f * f;
        }
    }
    __shared__ float sh[2][128];
    if (t < 128) { sh[0][t] = 0.f; sh[1][t] = 0.f; }
    __syncthreads();
    #pragma unroll
    for (int j = 0; j < 8; j++) {
        atomicAdd(&sh[0][oct * 8 + j], s1[j]);
        atomicAdd(&sh[1][oct * 8 + j], s2[j]);
    }
    __syncthreads();
    if (t < 128) {
        atomicAdd(&pooled[n * 128 + t], sh[0][t]);
        atomicAdd(&chsq[t], sh[1][t]);
    }
}

// -------------------------------------------------------------------- head
__global__ __launch_bounds__(256) void k_head(const float* __restrict__ pooled,
        const float* __restrict__ chsq, const float* __restrict__ g4,
        const float* __restrict__ b4, const float* __restrict__ fcw,
        const float* __restrict__ fcb, float* __restrict__ out) {
    __shared__ float feat[16 * 128];
    __shared__ float lg[160];
    __shared__ float corr[16];
    int t = threadIdx.x;
    if (t < 128) {
        float sum = 0.f;
        for (int n = 0; n < 16; n++) sum += pooled[n * 128 + t];
        float mean = sum * (1.f / CNT);
        float var = chsq[t] * (1.f / CNT) - mean * mean;
        float a = g4[t] * rsqrtf(var + EPS);
        float bb = b4[t] - mean * a;
        for (int n = 0; n < 16; n++)
            feat[n * 128 + t] = a * (pooled[n * 128 + t] * (1.f / (float)Sv)) + bb;
    }
    __syncthreads();
    if (t < 160) {
        int n = t / 10, j = t % 10;
        float acc = fcb[j];
        for (int c = 0; c < 128; c++) acc += feat[n * 128 + c] * fcw[j * 128 + c];
        lg[t] = acc;
    }
    __syncthreads();
    if (t < 16) {
        float mx = -1e30f;
        for (int j = 0; j < 10; j++) mx = fmaxf(mx, lg[t * 10 + j]);
        float se = 0.f;
        for (int j = 0; j < 10; j++) se += expf(lg[t * 10 + j] - mx);
        corr[t] = mx + logf(se);
    }
    __syncthreads();
    if (t < 160) out[t] = lg[t] - corr[t / 10];
}

// -------------------------------------------------------------------- launch
#define OFF_H3P 0L
#define OFF_H2P 110592000L
#define OFF_H1P 165888000L
#define OFF_H4  110592000L          // overlays h2p+h1p (dead at conv4 time)
#define OFF_WF2 200507392L
#define OFF_WF3 200617984L
#define OFF_WF4 201060352L
#define OFF_STATS 201945088L

extern "C" void kernel_launch(void* const* d_in, const int* in_sizes, int n_in,
                              void* d_out, int out_size, void* d_ws, size_t ws_size,
                              hipStream_t stream) {
    const float* x       = (const float*)d_in[0];
    const float* off_w   = (const float*)d_in[1];
    const float* off_b   = (const float*)d_in[2];
    const float* dconv_w = (const float*)d_in[3];
    const float* bn1_g   = (const float*)d_in[4];
    const float* bn1_b   = (const float*)d_in[5];
    const float* conv2_w = (const float*)d_in[6];
    const float* conv2_b = (const float*)d_in[7];
    const float* bn2_g   = (const float*)d_in[8];
    const float* bn2_b   = (const float*)d_in[9];
    const float* conv3_w = (const float*)d_in[10];
    const float* conv3_b = (const float*)d_in[11];
    const float* bn3_g   = (const float*)d_in[12];
    const float* bn3_b   = (const float*)d_in[13];
    const float* conv4_w = (const float*)d_in[14];
    const float* conv4_b = (const float*)d_in[15];
    const float* bn4_g   = (const float*)d_in[16];
    const float* bn4_b   = (const float*)d_in[17];
    const float* fc_w    = (const float*)d_in[18];
    const float* fc_b    = (const float*)d_in[19];

    float* out = (float*)d_out;
    float* offsets = out + 160;

    char* ws = (char*)d_ws;
    unsigned short* h3p = (unsigned short*)(ws + OFF_H3P);
    unsigned short* h2p = (unsigned short*)(ws + OFF_H2P);
    unsigned short* h1p = (unsigned short*)(ws + OFF_H1P);
    unsigned short* h4  = (unsigned short*)(ws + OFF_H4);
    unsigned short* wf2 = (unsigned short*)(ws + OFF_WF2);
    unsigned short* wf3 = (unsigned short*)(ws + OFF_WF3);
    unsigned short* wf4 = (unsigned short*)(ws + OFF_WF4);
    float* st = (float*)(ws + OFF_STATS);
    float* sums1 = st;        float* aff1 = st + 64;
    float* sums2 = st + 128;  float* aff2 = st + 256;
    float* sums3 = st + 384;  float* aff3 = st + 640;
    float* chsq4 = st + 896;  float* pooled = st + 1024;      // 16*128
    float* T2 = st + 4096;    float* T3 = st + 8192;   float* T4 = st + 16384;

    hipMemsetAsync(st, 0, 3072 * sizeof(float), stream);
    hipMemsetAsync(h1p, 0, 27648000L, stream);
    hipMemsetAsync(h2p, 0, 55296000L, stream);
    hipMemsetAsync(h3p, 0, 110592000L, stream);

    k_offsets<<<dim3(1372), 256, 0, stream>>>(x, off_w, off_b, offsets);
    k_deform<<<dim3(1372), 256, 0, stream>>>(x, offsets, dconv_w, h1p);

    k_stats_p<32><<<dim3(432), 256, 0, stream>>>(h1p, sums1);
    k_finalize<<<1, 32, 0, stream>>>(sums1, bn1_g, bn1_b, aff1, 32);
    k_wfrag<32, 64><<<dim3(27), 256, 0, stream>>>(conv2_w, aff1, wf2);
    k_btab<32, 64><<<dim3(7), 256, 0, stream>>>(conv2_w, conv2_b, aff1 + 32, T2);
    k_conv_mfma<32, 64, true><<<dim3(1372, 1), 256, 0, stream>>>(h1p, wf2, T2, h2p);

    k_stats_p<64><<<dim3(432), 256, 0, stream>>>(h2p, sums2);
    k_finalize<<<1, 64, 0, stream>>>(sums2, bn2_g, bn2_b, aff2, 64);
    k_wfrag<64, 128><<<dim3(108), 256, 0, stream>>>(conv3_w, aff2, wf3);
    k_btab<64, 128><<<dim3(14), 256, 0, stream>>>(conv3_w, conv3_b, aff2 + 64, T3);
    k_conv_mfma<64, 128, true><<<dim3(1372, 2), 256, 0, stream>>>(h2p, wf3, T3, h3p);

    k_stats_p<128><<<dim3(432), 256, 0, stream>>>(h3p, sums3);
    k_finalize<<<1, 128, 0, stream>>>(sums3, bn3_g, bn3_b, aff3, 128);
    k_wfrag<128, 128><<<dim3(216), 256, 0, stream>>>(conv4_w, aff3, wf4);
    k_btab<128, 128><<<dim3(14), 256, 0, stream>>>(conv4_w, conv4_b, aff3 + 128, T4);
    k_conv_mfma<128, 128, false><<<dim3(1372, 2), 256, 0, stream>>>(h3p, wf4, T4, h4);

    k_stats4<<<dim3(16, 28), 256, 0, stream>>>(h4, pooled, chsq4);
    k_head<<<1, 256, 0, stream>>>(pooled, chsq4, bn4_g, bn4_b, fc_w, fc_b, out);
}

// Round 3
// 1779.512 us; speedup vs baseline: 5.9820x; 1.3825x over previous
//
#include <hip/hip_runtime.h>
#include <math.h>

#define Sv 21952
#define HWc 784
#define CNT 351232.0f
#define EPS 1e-5f
#define PV 27000              // 30^3 padded volume per image
#define PT (16 * PV)          // padded positions total

typedef short bf16x8 __attribute__((ext_vector_type(8)));
typedef float f32x4 __attribute__((ext_vector_type(4)));
typedef unsigned short u16x8 __attribute__((ext_vector_type(8)));

__device__ __forceinline__ unsigned short f2bf(float f) {
    unsigned u = __float_as_uint(f);
    u = (u + 0x7FFFu + ((u >> 16) & 1u)) >> 16;
    return (unsigned short)u;
}
__device__ __forceinline__ float bf2f(unsigned short h) {
    return __uint_as_float(((unsigned)h) << 16);
}

// ---------------------------------------------------------------- offsets conv
__global__ __launch_bounds__(256) void k_offsets(const float* __restrict__ x,
        const float* __restrict__ ow, const float* __restrict__ ob,
        float* __restrict__ out) {
    __shared__ float w_s[81 * 27];
    __shared__ float b_s[81];
    for (int i = threadIdx.x; i < 81 * 27; i += 256) w_s[i] = ow[i];
    if (threadIdx.x < 81) b_s[threadIdx.x] = ob[threadIdx.x];
    __syncthreads();
    int idx = blockIdx.x * 256 + threadIdx.x;
    int n = idx / Sv, s = idx % Sv;
    int d = s / HWc, r = s % HWc, h = r / 28, w = r % 28;
    const float* xb = x + (long)n * Sv;
    float xv[27];
    #pragma unroll
    for (int dz = 0; dz < 3; dz++)
      #pragma unroll
      for (int dy = 0; dy < 3; dy++)
        #pragma unroll
        for (int dx = 0; dx < 3; dx++) {
            int zz = d + dz - 1, yy = h + dy - 1, xx = w + dx - 1;
            bool ok = (unsigned)zz < 28u && (unsigned)yy < 28u && (unsigned)xx < 28u;
            xv[dz * 9 + dy * 3 + dx] = ok ? xb[zz * HWc + yy * 28 + xx] : 0.f;
        }
    float* op = out + (long)n * 81 * Sv + s;
    for (int c = 0; c < 81; c++) {
        float acc = b_s[c];
        #pragma unroll
        for (int k = 0; k < 27; k++) acc += xv[k] * w_s[c * 27 + k];
        op[(long)c * Sv] = acc;
    }
}

// ---------------------------------------------------------------- deform conv
__device__ __forceinline__ float fetch_pad(const float* __restrict__ xb,
                                           int zq, int yq, int xq) {
    int z = zq - 1, y = yq - 1, xx = xq - 1;
    bool ok = (unsigned)z < 28u && (unsigned)y < 28u && (unsigned)xx < 28u;
    return ok ? xb[z * HWc + y * 28 + xx] : 0.f;
}

__global__ __launch_bounds__(256) void k_deform(const float* __restrict__ x,
        const float* __restrict__ off, const float* __restrict__ dw,
        unsigned short* __restrict__ h1p) {
    __shared__ float w_s[32 * 27];
    for (int i = threadIdx.x; i < 32 * 27; i += 256) w_s[i] = dw[i];
    __syncthreads();
    int idx = blockIdx.x * 256 + threadIdx.x;
    int n = idx / Sv, s = idx % Sv;
    int d = s / HWc, r = s % HWc, h = r / 28, w = r % 28;
    const float* xb = x + (long)n * Sv;
    const float* ofb = off + (long)n * 81 * Sv + s;
    float v[27];
    #pragma unroll
    for (int k = 0; k < 27; k++) {
        int ki = k / 9, kj = (k / 3) % 3, kl = k % 3;
        float pd = (float)(d + ki) + ofb[(long)k * Sv];
        float ph = (float)(h + kj) + ofb[(long)(27 + k) * Sv];
        float pw = (float)(w + kl) + ofb[(long)(54 + k) * Sv];
        float q0d = floorf(pd), q0h = floorf(ph), q0w = floorf(pw);
        float pcd = fminf(fmaxf(pd, 0.f), 29.f);
        float pch = fminf(fmaxf(ph, 0.f), 29.f);
        float pcw = fminf(fmaxf(pw, 0.f), 29.f);
        float q0cd = fminf(fmaxf(q0d, 0.f), 29.f);
        float q0ch = fminf(fmaxf(q0h, 0.f), 29.f);
        float q0cw = fminf(fmaxf(q0w, 0.f), 29.f);
        float q1cd = fminf(fmaxf(q0d + 1.f, 0.f), 29.f);
        float q1ch = fminf(fmaxf(q0h + 1.f, 0.f), 29.f);
        float q1cw = fminf(fmaxf(q0w + 1.f, 0.f), 29.f);
        float wz[2] = {1.f + (q0cd - pcd), 1.f - (q1cd - pcd)};
        float wy[2] = {1.f + (q0ch - pch), 1.f - (q1ch - pch)};
        float wx[2] = {1.f + (q0cw - pcw), 1.f - (q1cw - pcw)};
        int qz[2] = {(int)q0cd, (int)q1cd};
        int qy[2] = {(int)q0ch, (int)q1ch};
        int qx[2] = {(int)q0cw, (int)q1cw};
        float val = 0.f;
        #pragma unroll
        for (int cz = 0; cz < 2; cz++)
          #pragma unroll
          for (int cy = 0; cy < 2; cy++)
            #pragma unroll
            for (int cx = 0; cx < 2; cx++)
                val += wz[cz] * wy[cy] * wx[cx] * fetch_pad(xb, qz[cz], qy[cy], qx[cx]);
        v[k] = val;
    }
    unsigned pb = ((((unsigned)n * 30 + (d + 1)) * 30 + (h + 1)) * 30 + (w + 1)) * 32;
    unsigned short tmp[32];
    #pragma unroll
    for (int o = 0; o < 32; o++) {
        float acc = 0.f;
        #pragma unroll
        for (int k = 0; k < 27; k++) acc += v[k] * w_s[o * 27 + k];
        tmp[o] = f2bf(fmaxf(acc, 0.f));
    }
    u16x8* dst = (u16x8*)(h1p + pb);
    #pragma unroll
    for (int q = 0; q < 4; q++) dst[q] = ((u16x8*)tmp)[q];
}

// ------------------------------------------------- BN stats over padded buffer
template<int C>
__global__ __launch_bounds__(256) void k_stats_p(const unsigned short* __restrict__ buf,
        float* __restrict__ sums) {
    constexpr int G = C / 8;
    constexpr int P = 256 / G;
    int t = threadIdx.x;
    int oct = t % G, ps = t / G;
    float s1[8], s2[8];
    #pragma unroll
    for (int j = 0; j < 8; j++) { s1[j] = 0.f; s2[j] = 0.f; }
    for (int p = blockIdx.x * P + ps; p < PT; p += gridDim.x * P) {
        u16x8 v = *(const u16x8*)(buf + (long)p * C + oct * 8);
        #pragma unroll
        for (int j = 0; j < 8; j++) {
            float f = bf2f(v[j]);
            s1[j] += f; s2[j] += f * f;
        }
    }
    __shared__ float sh[2][C];
    if (t < C) { sh[0][t] = 0.f; sh[1][t] = 0.f; }
    __syncthreads();
    #pragma unroll
    for (int j = 0; j < 8; j++) {
        atomicAdd(&sh[0][oct * 8 + j], s1[j]);
        atomicAdd(&sh[1][oct * 8 + j], s2[j]);
    }
    __syncthreads();
    if (t < C) { atomicAdd(&sums[t], sh[0][t]); atomicAdd(&sums[C + t], sh[1][t]); }
}

__global__ void k_finalize(const float* __restrict__ sums, const float* __restrict__ g,
        const float* __restrict__ bb, float* __restrict__ aff, int C) {
    int c = threadIdx.x;
    if (c < C) {
        float mean = sums[c] * (1.f / CNT);
        float var = sums[C + c] * (1.f / CNT) - mean * mean;
        float a = g[c] * rsqrtf(var + EPS);
        aff[c] = a;
        aff[C + c] = bb[c] - mean * a;
    }
}

// ---------------------------------------------- weight prep: B-fragment swizzle
template<int CI, int COT>
__global__ __launch_bounds__(256) void k_wfrag(const float* __restrict__ w,
        const float* __restrict__ affa, unsigned short* __restrict__ wf) {
    int tid = blockIdx.x * 256 + threadIdx.x;
    int lane = tid & 63, rest = tid >> 6;
    int gnt = rest % (COT / 16); rest /= (COT / 16);
    int kc = rest % (CI / 32);
    int tap = rest / (CI / 32);
    if (tap >= 27) return;
    int co = gnt * 16 + (lane & 15);
    unsigned short tmp[8];
    #pragma unroll
    for (int j = 0; j < 8; j++) {
        int ci = kc * 32 + (lane >> 4) * 8 + j;
        tmp[j] = f2bf(w[((long)co * CI + ci) * 27 + tap] * affa[ci]);
    }
    *(u16x8*)(wf + (long)tid * 8) = *(u16x8*)tmp;
}

template<int CI, int COT>
__global__ void k_btab(const float* __restrict__ w, const float* __restrict__ bias,
        const float* __restrict__ affb, float* __restrict__ T) {
    int tid = blockIdx.x * 256 + threadIdx.x;
    if (tid >= 27 * COT) return;
    int co = tid % COT, cls = tid / COT;
    int xc = cls % 3, yc = (cls / 3) % 3, zc = cls / 9;
    float val = bias[co];
    for (int t = 0; t < 27; t++) {
        int dx = t % 3, dy = (t / 3) % 3, dz = t / 9;
        bool ok = (zc == 1 || (zc == 0 && dz >= 1) || (zc == 2 && dz <= 1))
               && (yc == 1 || (yc == 0 && dy >= 1) || (yc == 2 && dy <= 1))
               && (xc == 1 || (xc == 0 && dx >= 1) || (xc == 2 && dx <= 1));
        if (ok) {
            float s = 0.f;
            for (int ci = 0; ci < CI; ci++) s += w[((long)co * CI + ci) * 27 + t] * affb[ci];
            val += s;
        }
    }
    T[cls * COT + co] = val;
}

// ------------------------------------------------------ MFMA implicit-GEMM conv
// LDS-staged: block = (z:1, y:4, x:28(+4 clip)) x COT.  WM=2 fixed; WN in {1,2}.
// Per 32-ch chunk: stage 3x6x30 halo in LDS (plane-per-quad layout), then
// 27 taps read A via ds_read_b128 at wave-uniform tap offsets; B from global.
template<int CI, int COT, int WN, bool PAD_OUT>
__global__ __launch_bounds__(WN * 128) void k_conv_mfma(
        const unsigned short* __restrict__ in,
        const unsigned short* __restrict__ wfrag,
        const float* __restrict__ Ttab,
        unsigned short* __restrict__ out) {
    constexpr int KC = CI / 32;
    constexpr int NTT = COT / 16;
    constexpr int NT = WN * 128;          // threads
    constexpr int CP = 3 * 6 * 30;        // 540 halo positions per chunk
    constexpr int CU16 = CP * 4;          // 2160 16B units per chunk
    __shared__ unsigned short lds[CP * 32];   // 34560 B

    int tid = threadIdx.x, wv = tid >> 6, lane = tid & 63;
    int lrow = lane & 15, quad = lane >> 4;
    int wv_m = wv & 1, wv_n = wv >> 1;
    int bx = blockIdx.x;
    int n = bx / 196;
    int rem = bx % 196;
    int z0 = rem / 7;
    int y0 = (rem % 7) * 4;
    long gpos0 = ((long)(n * 30 + z0) * 30 + y0) * 30;

    // per-lane A bases (bytes into lds), tap-independent
    int baseA[4];
    #pragma unroll
    for (int mt = 0; mt < 4; mt++) {
        int row = wv_m * 64 + mt * 16 + lrow;
        int yl = row >> 5;
        int x = row & 31; if (x > 27) x = 27;       // clip lanes (masked at store)
        baseA[mt] = ((yl * 30 + x) + quad * CP) * 16;
    }

    f32x4 acc[4][4];
    #pragma unroll
    for (int mt = 0; mt < 4; mt++)
        #pragma unroll
        for (int nt = 0; nt < 4; nt++)
            #pragma unroll
            for (int e = 0; e < 4; e++) acc[mt][nt][e] = 0.f;

    for (int kc = 0; kc < KC; kc++) {
        if (kc) __syncthreads();
        // ---- stage chunk kc: grouped loads (4 in flight) then LDS writes
        for (int i0 = 0; i0 < CU16; i0 += NT * 4) {
            u16x8 t[4];
            #pragma unroll
            for (int j = 0; j < 4; j++) {
                int u = i0 + j * NT + tid;
                if (u < CU16) {
                    int q = u / CP, p = u - q * CP;
                    int zl = p / 180, r = p - zl * 180;
                    int yl = r / 30, xl = r - yl * 30;
                    t[j] = *(const u16x8*)(in +
                        (gpos0 + zl * 900 + yl * 30 + xl) * CI + kc * 32 + q * 8);
                }
            }
            #pragma unroll
            for (int j = 0; j < 4; j++) {
                int u = i0 + j * NT + tid;
                if (u < CU16) *(u16x8*)(lds + u * 8) = t[j];
            }
        }
        __syncthreads();
        // ---- 27 taps from LDS
        for (int tap = 0; tap < 27; tap++) {
            int dz = tap / 9, dy = (tap / 3) % 3, dx = tap % 3;
            int td = ((dz * 6 + dy) * 30 + dx) * 16;
            const unsigned short* pw =
                wfrag + (long)((tap * KC + kc) * NTT + wv_n * 4) * 512 + lane * 8;
            bf16x8 b[4];
            #pragma unroll
            for (int nt = 0; nt < 4; nt++)
                b[nt] = *(const bf16x8*)(pw + nt * 512);
            bf16x8 a[4];
            #pragma unroll
            for (int mt = 0; mt < 4; mt++)
                a[mt] = *(const bf16x8*)((const char*)lds + baseA[mt] + td);
            #pragma unroll
            for (int mt = 0; mt < 4; mt++)
                #pragma unroll
                for (int nt = 0; nt < 4; nt++)
                    acc[mt][nt] = __builtin_amdgcn_mfma_f32_16x16x32_bf16(
                        a[mt], b[nt], acc[mt][nt], 0, 0, 0);
        }
    }

    // ---- epilogue
    #pragma unroll
    for (int mt = 0; mt < 4; mt++) {
        #pragma unroll
        for (int e = 0; e < 4; e++) {
            int row = wv_m * 64 + mt * 16 + quad * 4 + e;
            int y = y0 + (row >> 5);
            int x = row & 31;
            if (x >= 28) continue;
            int zc = (z0 == 0) ? 0 : ((z0 == 27) ? 2 : 1);
            int yc = (y == 0) ? 0 : ((y == 27) ? 2 : 1);
            int xc = (x == 0) ? 0 : ((x == 27) ? 2 : 1);
            int cls = (zc * 3 + yc) * 3 + xc;
            long ob;
            if (PAD_OUT)
                ob = ((long)((n * 30 + z0 + 1) * 30 + y + 1) * 30 + x + 1) * COT;
            else
                ob = ((long)n * Sv + z0 * HWc + y * 28 + x) * COT;
            #pragma unroll
            for (int nt = 0; nt < 4; nt++) {
                int co = wv_n * 64 + nt * 16 + lrow;
                float v = acc[mt][nt][e] + Ttab[cls * COT + co];
                out[ob + co] = f2bf(fmaxf(v, 0.f));
            }
        }
    }
}

// ------------------------------------------- conv4 pooled/sumsq (h4 unpadded)
__global__ __launch_bounds__(256) void k_stats4(const unsigned short* __restrict__ h4,
        float* __restrict__ pooled, float* __restrict__ chsq) {
    int n = blockIdx.x, zs = blockIdx.y;
    int t = threadIdx.x;
    int oct = t % 16, ps = t / 16;
    long base = (long)n * Sv + zs * HWc;
    float s1[8], s2[8];
    #pragma unroll
    for (int j = 0; j < 8; j++) { s1[j] = 0.f; s2[j] = 0.f; }
    for (int p = ps; p < HWc; p += 16) {
        u16x8 v = *(const u16x8*)(h4 + (base + p) * 128 + oct * 8);
        #pragma unroll
        for (int j = 0; j < 8; j++) {
            float f = bf2f(v[j]);
            s1[j] += f; s2[j] += f * f;
        }
    }
    __shared__ float sh[2][128];
    if (t < 128) { sh[0][t] = 0.f; sh[1][t] = 0.f; }
    __syncthreads();
    #pragma unroll
    for (int j = 0; j < 8; j++) {
        atomicAdd(&sh[0][oct * 8 + j], s1[j]);
        atomicAdd(&sh[1][oct * 8 + j], s2[j]);
    }
    __syncthreads();
    if (t < 128) {
        atomicAdd(&pooled[n * 128 + t], sh[0][t]);
        atomicAdd(&chsq[t], sh[1][t]);
    }
}

// -------------------------------------------------------------------- head
__global__ __launch_bounds__(256) void k_head(const float* __restrict__ pooled,
        const float* __restrict__ chsq, const float* __restrict__ g4,
        const float* __restrict__ b4, const float* __restrict__ fcw,
        const float* __restrict__ fcb, float* __restrict__ out) {
    __shared__ float feat[16 * 128];
    __shared__ float lg[160];
    __shared__ float corr[16];
    int t = threadIdx.x;
    if (t < 128) {
        float sum = 0.f;
        for (int n = 0; n < 16; n++) sum += pooled[n * 128 + t];
        float mean = sum * (1.f / CNT);
        float var = chsq[t] * (1.f / CNT) - mean * mean;
        float a = g4[t] * rsqrtf(var + EPS);
        float bb = b4[t] - mean * a;
        for (int n = 0; n < 16; n++)
            feat[n * 128 + t] = a * (pooled[n * 128 + t] * (1.f / (float)Sv)) + bb;
    }
    __syncthreads();
    if (t < 160) {
        int n = t / 10, j = t % 10;
        float acc = fcb[j];
        for (int c = 0; c < 128; c++) acc += feat[n * 128 + c] * fcw[j * 128 + c];
        lg[t] = acc;
    }
    __syncthreads();
    if (t < 16) {
        float mx = -1e30f;
        for (int j = 0; j < 10; j++) mx = fmaxf(mx, lg[t * 10 + j]);
        float se = 0.f;
        for (int j = 0; j < 10; j++) se += expf(lg[t * 10 + j] - mx);
        corr[t] = mx + logf(se);
    }
    __syncthreads();
    if (t < 160) out[t] = lg[t] - corr[t / 10];
}

// -------------------------------------------------------------------- launch
#define OFF_H3P 0L
#define OFF_H2P 110592000L
#define OFF_H1P 165888000L
#define OFF_H4  110592000L
#define OFF_WF2 200507392L
#define OFF_WF3 200617984L
#define OFF_WF4 201060352L
#define OFF_STATS 201945088L

extern "C" void kernel_launch(void* const* d_in, const int* in_sizes, int n_in,
                              void* d_out, int out_size, void* d_ws, size_t ws_size,
                              hipStream_t stream) {
    const float* x       = (const float*)d_in[0];
    const float* off_w   = (const float*)d_in[1];
    const float* off_b   = (const float*)d_in[2];
    const float* dconv_w = (const float*)d_in[3];
    const float* bn1_g   = (const float*)d_in[4];
    const float* bn1_b   = (const float*)d_in[5];
    const float* conv2_w = (const float*)d_in[6];
    const float* conv2_b = (const float*)d_in[7];
    const float* bn2_g   = (const float*)d_in[8];
    const float* bn2_b   = (const float*)d_in[9];
    const float* conv3_w = (const float*)d_in[10];
    const float* conv3_b = (const float*)d_in[11];
    const float* bn3_g   = (const float*)d_in[12];
    const float* bn3_b   = (const float*)d_in[13];
    const float* conv4_w = (const float*)d_in[14];
    const float* conv4_b = (const float*)d_in[15];
    const float* bn4_g   = (const float*)d_in[16];
    const float* bn4_b   = (const float*)d_in[17];
    const float* fc_w    = (const float*)d_in[18];
    const float* fc_b    = (const float*)d_in[19];

    float* out = (float*)d_out;
    float* offsets = out + 160;

    char* ws = (char*)d_ws;
    unsigned short* h3p = (unsigned short*)(ws + OFF_H3P);
    unsigned short* h2p = (unsigned short*)(ws + OFF_H2P);
    unsigned short* h1p = (unsigned short*)(ws + OFF_H1P);
    unsigned short* h4  = (unsigned short*)(ws + OFF_H4);
    unsigned short* wf2 = (unsigned short*)(ws + OFF_WF2);
    unsigned short* wf3 = (unsigned short*)(ws + OFF_WF3);
    unsigned short* wf4 = (unsigned short*)(ws + OFF_WF4);
    float* st = (float*)(ws + OFF_STATS);
    float* sums1 = st;        float* aff1 = st + 64;
    float* sums2 = st + 128;  float* aff2 = st + 256;
    float* sums3 = st + 384;  float* aff3 = st + 640;
    float* chsq4 = st + 896;  float* pooled = st + 1024;
    float* T2 = st + 4096;    float* T3 = st + 8192;   float* T4 = st + 16384;

    hipMemsetAsync(st, 0, 3072 * sizeof(float), stream);
    hipMemsetAsync(h1p, 0, 27648000L, stream);
    hipMemsetAsync(h2p, 0, 55296000L, stream);
    hipMemsetAsync(h3p, 0, 110592000L, stream);

    k_offsets<<<dim3(1372), 256, 0, stream>>>(x, off_w, off_b, offsets);
    k_deform<<<dim3(1372), 256, 0, stream>>>(x, offsets, dconv_w, h1p);

    k_stats_p<32><<<dim3(432), 256, 0, stream>>>(h1p, sums1);
    k_finalize<<<1, 32, 0, stream>>>(sums1, bn1_g, bn1_b, aff1, 32);
    k_wfrag<32, 64><<<dim3(27), 256, 0, stream>>>(conv2_w, aff1, wf2);
    k_btab<32, 64><<<dim3(7), 256, 0, stream>>>(conv2_w, conv2_b, aff1 + 32, T2);
    k_conv_mfma<32, 64, 1, true><<<dim3(3136), 128, 0, stream>>>(h1p, wf2, T2, h2p);

    k_stats_p<64><<<dim3(432), 256, 0, stream>>>(h2p, sums2);
    k_finalize<<<1, 64, 0, stream>>>(sums2, bn2_g, bn2_b, aff2, 64);
    k_wfrag<64, 128><<<dim3(108), 256, 0, stream>>>(conv3_w, aff2, wf3);
    k_btab<64, 128><<<dim3(14), 256, 0, stream>>>(conv3_w, conv3_b, aff2 + 64, T3);
    k_conv_mfma<64, 128, 2, true><<<dim3(3136), 256, 0, stream>>>(h2p, wf3, T3, h3p);

    k_stats_p<128><<<dim3(432), 256, 0, stream>>>(h3p, sums3);
    k_finalize<<<1, 128, 0, stream>>>(sums3, bn3_g, bn3_b, aff3, 128);
    k_wfrag<128, 128><<<dim3(216), 256, 0, stream>>>(conv4_w, aff3, wf4);
    k_btab<128, 128><<<dim3(14), 256, 0, stream>>>(conv4_w, conv4_b, aff3 + 128, T4);
    k_conv_mfma<128, 128, 2, false><<<dim3(3136), 256, 0, stream>>>(h3p, wf4, T4, h4);

    k_stats4<<<dim3(16, 28), 256, 0, stream>>>(h4, pooled, chsq4);
    k_head<<<1, 256, 0, stream>>>(pooled, chsq4, bn4_g, bn4_b, fc_w, fc_b, out);
}

// Round 4
// 1719.911 us; speedup vs baseline: 6.1893x; 1.0347x over previous
//
#include <hip/hip_runtime.h>
#include <math.h>

#define Sv 21952
#define HWc 784
#define CNT 351232.0f
#define EPS 1e-5f
#define PV 27000              // 30^3 padded volume per image
#define PT (16 * PV)          // padded positions total

typedef short bf16x8 __attribute__((ext_vector_type(8)));
typedef float f32x4 __attribute__((ext_vector_type(4)));
typedef unsigned short u16x8 __attribute__((ext_vector_type(8)));

__device__ __forceinline__ unsigned short f2bf(float f) {
    unsigned u = __float_as_uint(f);
    u = (u + 0x7FFFu + ((u >> 16) & 1u)) >> 16;
    return (unsigned short)u;
}
__device__ __forceinline__ float bf2f(unsigned short h) {
    return __uint_as_float(((unsigned)h) << 16);
}

// ---------------------------------------------------------------- offsets conv
__global__ __launch_bounds__(256) void k_offsets(const float* __restrict__ x,
        const float* __restrict__ ow, const float* __restrict__ ob,
        float* __restrict__ out) {
    __shared__ float w_s[81 * 27];
    __shared__ float b_s[81];
    for (int i = threadIdx.x; i < 81 * 27; i += 256) w_s[i] = ow[i];
    if (threadIdx.x < 81) b_s[threadIdx.x] = ob[threadIdx.x];
    __syncthreads();
    int idx = blockIdx.x * 256 + threadIdx.x;
    int n = idx / Sv, s = idx % Sv;
    int d = s / HWc, r = s % HWc, h = r / 28, w = r % 28;
    const float* xb = x + (long)n * Sv;
    float xv[27];
    #pragma unroll
    for (int dz = 0; dz < 3; dz++)
      #pragma unroll
      for (int dy = 0; dy < 3; dy++)
        #pragma unroll
        for (int dx = 0; dx < 3; dx++) {
            int zz = d + dz - 1, yy = h + dy - 1, xx = w + dx - 1;
            bool ok = (unsigned)zz < 28u && (unsigned)yy < 28u && (unsigned)xx < 28u;
            xv[dz * 9 + dy * 3 + dx] = ok ? xb[zz * HWc + yy * 28 + xx] : 0.f;
        }
    float* op = out + (long)n * 81 * Sv + s;
    for (int c = 0; c < 81; c++) {
        float acc = b_s[c];
        #pragma unroll
        for (int k = 0; k < 27; k++) acc += xv[k] * w_s[c * 27 + k];
        op[(long)c * Sv] = acc;
    }
}

// ---------------------------------------------------------------- deform conv
__device__ __forceinline__ float fetch_pad(const float* __restrict__ xb,
                                           int zq, int yq, int xq) {
    int z = zq - 1, y = yq - 1, xx = xq - 1;
    bool ok = (unsigned)z < 28u && (unsigned)y < 28u && (unsigned)xx < 28u;
    return ok ? xb[z * HWc + y * 28 + xx] : 0.f;
}

__global__ __launch_bounds__(256) void k_deform(const float* __restrict__ x,
        const float* __restrict__ off, const float* __restrict__ dw,
        unsigned short* __restrict__ h1p) {
    __shared__ float w_s[32 * 27];
    for (int i = threadIdx.x; i < 32 * 27; i += 256) w_s[i] = dw[i];
    __syncthreads();
    int idx = blockIdx.x * 256 + threadIdx.x;
    int n = idx / Sv, s = idx % Sv;
    int d = s / HWc, r = s % HWc, h = r / 28, w = r % 28;
    const float* xb = x + (long)n * Sv;
    const float* ofb = off + (long)n * 81 * Sv + s;
    float v[27];
    #pragma unroll
    for (int k = 0; k < 27; k++) {
        int ki = k / 9, kj = (k / 3) % 3, kl = k % 3;
        float pd = (float)(d + ki) + ofb[(long)k * Sv];
        float ph = (float)(h + kj) + ofb[(long)(27 + k) * Sv];
        float pw = (float)(w + kl) + ofb[(long)(54 + k) * Sv];
        float q0d = floorf(pd), q0h = floorf(ph), q0w = floorf(pw);
        float pcd = fminf(fmaxf(pd, 0.f), 29.f);
        float pch = fminf(fmaxf(ph, 0.f), 29.f);
        float pcw = fminf(fmaxf(pw, 0.f), 29.f);
        float q0cd = fminf(fmaxf(q0d, 0.f), 29.f);
        float q0ch = fminf(fmaxf(q0h, 0.f), 29.f);
        float q0cw = fminf(fmaxf(q0w, 0.f), 29.f);
        float q1cd = fminf(fmaxf(q0d + 1.f, 0.f), 29.f);
        float q1ch = fminf(fmaxf(q0h + 1.f, 0.f), 29.f);
        float q1cw = fminf(fmaxf(q0w + 1.f, 0.f), 29.f);
        float wz[2] = {1.f + (q0cd - pcd), 1.f - (q1cd - pcd)};
        float wy[2] = {1.f + (q0ch - pch), 1.f - (q1ch - pch)};
        float wx[2] = {1.f + (q0cw - pcw), 1.f - (q1cw - pcw)};
        int qz[2] = {(int)q0cd, (int)q1cd};
        int qy[2] = {(int)q0ch, (int)q1ch};
        int qx[2] = {(int)q0cw, (int)q1cw};
        float val = 0.f;
        #pragma unroll
        for (int cz = 0; cz < 2; cz++)
          #pragma unroll
          for (int cy = 0; cy < 2; cy++)
            #pragma unroll
            for (int cx = 0; cx < 2; cx++)
                val += wz[cz] * wy[cy] * wx[cx] * fetch_pad(xb, qz[cz], qy[cy], qx[cx]);
        v[k] = val;
    }
    unsigned pb = ((((unsigned)n * 30 + (d + 1)) * 30 + (h + 1)) * 30 + (w + 1)) * 32;
    unsigned short tmp[32];
    #pragma unroll
    for (int o = 0; o < 32; o++) {
        float acc = 0.f;
        #pragma unroll
        for (int k = 0; k < 27; k++) acc += v[k] * w_s[o * 27 + k];
        tmp[o] = f2bf(fmaxf(acc, 0.f));
    }
    u16x8* dst = (u16x8*)(h1p + pb);
    #pragma unroll
    for (int q = 0; q < 4; q++) dst[q] = ((u16x8*)tmp)[q];
}

// ------------------------------------------------- BN stats over padded buffer
template<int C>
__global__ __launch_bounds__(256) void k_stats_p(const unsigned short* __restrict__ buf,
        float* __restrict__ sums) {
    constexpr int G = C / 8;
    constexpr int P = 256 / G;
    int t = threadIdx.x;
    int oct = t % G, ps = t / G;
    float s1[8], s2[8];
    #pragma unroll
    for (int j = 0; j < 8; j++) { s1[j] = 0.f; s2[j] = 0.f; }
    for (int p = blockIdx.x * P + ps; p < PT; p += gridDim.x * P) {
        u16x8 v = *(const u16x8*)(buf + (long)p * C + oct * 8);
        #pragma unroll
        for (int j = 0; j < 8; j++) {
            float f = bf2f(v[j]);
            s1[j] += f; s2[j] += f * f;
        }
    }
    __shared__ float sh[2][C];
    if (t < C) { sh[0][t] = 0.f; sh[1][t] = 0.f; }
    __syncthreads();
    #pragma unroll
    for (int j = 0; j < 8; j++) {
        atomicAdd(&sh[0][oct * 8 + j], s1[j]);
        atomicAdd(&sh[1][oct * 8 + j], s2[j]);
    }
    __syncthreads();
    if (t < C) { atomicAdd(&sums[t], sh[0][t]); atomicAdd(&sums[C + t], sh[1][t]); }
}

__global__ void k_finalize(const float* __restrict__ sums, const float* __restrict__ g,
        const float* __restrict__ bb, float* __restrict__ aff, int C) {
    int c = threadIdx.x;
    if (c < C) {
        float mean = sums[c] * (1.f / CNT);
        float var = sums[C + c] * (1.f / CNT) - mean * mean;
        float a = g[c] * rsqrtf(var + EPS);
        aff[c] = a;
        aff[C + c] = bb[c] - mean * a;
    }
}

// ---------------------------------------------- weight prep: B-fragment swizzle
// layout: wf[kc][tap][gnt][lane][8]  (tap-contiguous inner loop in conv kernel)
template<int CI, int COT>
__global__ __launch_bounds__(256) void k_wfrag(const float* __restrict__ w,
        const float* __restrict__ affa, unsigned short* __restrict__ wf) {
    int tid = blockIdx.x * 256 + threadIdx.x;
    int lane = tid & 63, rest = tid >> 6;
    constexpr int NTT = COT / 16;
    int gnt = rest % NTT; rest /= NTT;
    int kc = rest % (CI / 32);
    int tap = rest / (CI / 32);
    if (tap >= 27) return;
    int co = gnt * 16 + (lane & 15);
    unsigned short tmp[8];
    #pragma unroll
    for (int j = 0; j < 8; j++) {
        int ci = kc * 32 + (lane >> 4) * 8 + j;
        tmp[j] = f2bf(w[((long)co * CI + ci) * 27 + tap] * affa[ci]);
    }
    long oidx = (((long)kc * 27 + tap) * NTT + gnt) * 512 + lane * 8;
    *(u16x8*)(wf + oidx) = *(u16x8*)tmp;
}

template<int CI, int COT>
__global__ void k_btab(const float* __restrict__ w, const float* __restrict__ bias,
        const float* __restrict__ affb, float* __restrict__ T) {
    int tid = blockIdx.x * 256 + threadIdx.x;
    if (tid >= 27 * COT) return;
    int co = tid % COT, cls = tid / COT;
    int xc = cls % 3, yc = (cls / 3) % 3, zc = cls / 9;
    float val = bias[co];
    for (int t = 0; t < 27; t++) {
        int dx = t % 3, dy = (t / 3) % 3, dz = t / 9;
        bool ok = (zc == 1 || (zc == 0 && dz >= 1) || (zc == 2 && dz <= 1))
               && (yc == 1 || (yc == 0 && dy >= 1) || (yc == 2 && dy <= 1))
               && (xc == 1 || (xc == 0 && dx >= 1) || (xc == 2 && dx <= 1));
        if (ok) {
            float s = 0.f;
            for (int ci = 0; ci < CI; ci++) s += w[((long)co * CI + ci) * 27 + t] * affb[ci];
            val += s;
        }
    }
    T[cls * COT + co] = val;
}

// ------------------------------------------------------ MFMA implicit-GEMM conv
// Pipelined: per 32-ch chunk, stage 3x6x30 halo via register prefetch (next
// chunk's loads overlap this chunk's 27-tap MFMA compute). Quad stride padded
// 540->541 to decorrelate LDS banks. XCD-swizzled block order for L2 locality.
template<int CI, int COT, int WN, bool PAD_OUT>
__global__ __launch_bounds__(WN * 128) void k_conv_mfma(
        const unsigned short* __restrict__ in,
        const unsigned short* __restrict__ wfrag,
        const float* __restrict__ Ttab,
        unsigned short* __restrict__ out) {
    constexpr int KC = CI / 32;
    constexpr int NTT = COT / 16;
    constexpr int NT = WN * 128;
    constexpr int CP = 540;               // 3*6*30 halo positions
    constexpr int CPP = 541;              // padded quad stride (16B units)
    constexpr int CU16 = CP * 4;          // 2160 16B units per chunk
    constexpr int NLOAD = (CU16 + NT - 1) / NT;
    __shared__ unsigned short lds[CPP * 4 * 8];   // 34624 B

    int tid = threadIdx.x, wv = tid >> 6, lane = tid & 63;
    int lrow = lane & 15, quad = lane >> 4;
    int wv_m = wv & 1, wv_n = wv >> 1;

    // XCD swizzle: each XCD (bx%8) owns 2 images, z-major within
    int bx = blockIdx.x;
    int xcd = bx & 7, loc = bx >> 3;          // grid 3136 = 8*392
    int n = xcd * 2 + loc / 196;
    int rem = loc % 196;
    int z0 = rem / 7;
    int y0 = (rem % 7) * 4;
    const unsigned short* src = in + ((long)((n * 30 + z0) * 30 + y0) * 30) * CI;

    // chunk-invariant staging offsets (threads past CU16 clamp -> harmless dup)
    int src_off[NLOAD], dst_off[NLOAD];
    #pragma unroll
    for (int j = 0; j < NLOAD; j++) {
        int u = j * NT + tid;
        if (u >= CU16) u = CU16 - 1;
        int q = u / CP, p = u - q * CP;
        int zl = p / 180, r = p - zl * 180;
        int yl = r / 30, xl = r - yl * 30;
        src_off[j] = (zl * 900 + yl * 30 + xl) * CI + q * 8;
        dst_off[j] = (q * CPP + p) * 8;
    }

    // per-lane A bases (bytes into lds), tap-independent
    int baseA[4];
    #pragma unroll
    for (int mt = 0; mt < 4; mt++) {
        int row = wv_m * 64 + mt * 16 + lrow;
        int yl = row >> 5;
        int x = row & 31; if (x > 27) x = 27;     // clip lanes (masked at store)
        baseA[mt] = (quad * CPP + yl * 30 + x) * 16;
    }

    f32x4 acc[4][4];
    #pragma unroll
    for (int mt = 0; mt < 4; mt++)
        #pragma unroll
        for (int nt = 0; nt < 4; nt++)
            #pragma unroll
            for (int e = 0; e < 4; e++) acc[mt][nt][e] = 0.f;

    u16x8 pf[KC > 1 ? NLOAD : 1];
    if constexpr (KC > 1) {
        #pragma unroll
        for (int j = 0; j < NLOAD; j++) pf[j] = *(const u16x8*)(src + src_off[j]);
    }

    for (int kc = 0; kc < KC; kc++) {
        if (kc) __syncthreads();
        if constexpr (KC > 1) {
            #pragma unroll
            for (int j = 0; j < NLOAD; j++) *(u16x8*)(lds + dst_off[j]) = pf[j];
        } else {
            #pragma unroll
            for (int j = 0; j < NLOAD; j++) {
                u16x8 t = *(const u16x8*)(src + src_off[j]);
                *(u16x8*)(lds + dst_off[j]) = t;
            }
        }
        __syncthreads();
        if constexpr (KC > 1) {
            if (kc + 1 < KC) {
                int ko = (kc + 1) * 32;
                #pragma unroll
                for (int j = 0; j < NLOAD; j++)
                    pf[j] = *(const u16x8*)(src + src_off[j] + ko);
            }
        }
        const unsigned short* pwk =
            wfrag + ((long)(kc * 27) * NTT + wv_n * 4) * 512 + lane * 8;
        #pragma unroll
        for (int dz = 0; dz < 3; dz++) {
            #pragma unroll
            for (int t9 = 0; t9 < 9; t9++) {
                int tap = dz * 9 + t9;
                int td = ((dz * 6 + t9 / 3) * 30 + t9 % 3) * 16;
                const unsigned short* pw = pwk + (long)tap * NTT * 512;
                bf16x8 b[4];
                #pragma unroll
                for (int nt = 0; nt < 4; nt++)
                    b[nt] = *(const bf16x8*)(pw + nt * 512);
                bf16x8 a[4];
                #pragma unroll
                for (int mt = 0; mt < 4; mt++)
                    a[mt] = *(const bf16x8*)((const char*)lds + baseA[mt] + td);
                #pragma unroll
                for (int mt = 0; mt < 4; mt++)
                    #pragma unroll
                    for (int nt = 0; nt < 4; nt++)
                        acc[mt][nt] = __builtin_amdgcn_mfma_f32_16x16x32_bf16(
                            a[mt], b[nt], acc[mt][nt], 0, 0, 0);
            }
        }
    }

    // ---- epilogue
    #pragma unroll
    for (int mt = 0; mt < 4; mt++) {
        #pragma unroll
        for (int e = 0; e < 4; e++) {
            int row = wv_m * 64 + mt * 16 + quad * 4 + e;
            int y = y0 + (row >> 5);
            int x = row & 31;
            if (x >= 28) continue;
            int zc = (z0 == 0) ? 0 : ((z0 == 27) ? 2 : 1);
            int yc = (y == 0) ? 0 : ((y == 27) ? 2 : 1);
            int xc = (x == 0) ? 0 : ((x == 27) ? 2 : 1);
            int cls = (zc * 3 + yc) * 3 + xc;
            long ob;
            if (PAD_OUT)
                ob = ((long)((n * 30 + z0 + 1) * 30 + y + 1) * 30 + x + 1) * COT;
            else
                ob = ((long)n * Sv + z0 * HWc + y * 28 + x) * COT;
            #pragma unroll
            for (int nt = 0; nt < 4; nt++) {
                int co = wv_n * 64 + nt * 16 + lrow;
                float v = acc[mt][nt][e] + Ttab[cls * COT + co];
                out[ob + co] = f2bf(fmaxf(v, 0.f));
            }
        }
    }
}

// ------------------------------------------- conv4 pooled/sumsq (h4 unpadded)
__global__ __launch_bounds__(256) void k_stats4(const unsigned short* __restrict__ h4,
        float* __restrict__ pooled, float* __restrict__ chsq) {
    int n = blockIdx.x, zs = blockIdx.y;
    int t = threadIdx.x;
    int oct = t % 16, ps = t / 16;
    long base = (long)n * Sv + zs * HWc;
    float s1[8], s2[8];
    #pragma unroll
    for (int j = 0; j < 8; j++) { s1[j] = 0.f; s2[j] = 0.f; }
    for (int p = ps; p < HWc; p += 16) {
        u16x8 v = *(const u16x8*)(h4 + (base + p) * 128 + oct * 8);
        #pragma unroll
        for (int j = 0; j < 8; j++) {
            float f = bf2f(v[j]);
            s1[j] += f; s2[j] += f * f;
        }
    }
    __shared__ float sh[2][128];
    if (t < 128) { sh[0][t] = 0.f; sh[1][t] = 0.f; }
    __syncthreads();
    #pragma unroll
    for (int j = 0; j < 8; j++) {
        atomicAdd(&sh[0][oct * 8 + j], s1[j]);
        atomicAdd(&sh[1][oct * 8 + j], s2[j]);
    }
    __syncthreads();
    if (t < 128) {
        atomicAdd(&pooled[n * 128 + t], sh[0][t]);
        atomicAdd(&chsq[t], sh[1][t]);
    }
}

// -------------------------------------------------------------------- head
__global__ __launch_bounds__(256) void k_head(const float* __restrict__ pooled,
        const float* __restrict__ chsq, const float* __restrict__ g4,
        const float* __restrict__ b4, const float* __restrict__ fcw,
        const float* __restrict__ fcb, float* __restrict__ out) {
    __shared__ float feat[16 * 128];
    __shared__ float lg[160];
    __shared__ float corr[16];
    int t = threadIdx.x;
    if (t < 128) {
        float sum = 0.f;
        for (int n = 0; n < 16; n++) sum += pooled[n * 128 + t];
        float mean = sum * (1.f / CNT);
        float var = chsq[t] * (1.f / CNT) - mean * mean;
        float a = g4[t] * rsqrtf(var + EPS);
        float bb = b4[t] - mean * a;
        for (int n = 0; n < 16; n++)
            feat[n * 128 + t] = a * (pooled[n * 128 + t] * (1.f / (float)Sv)) + bb;
    }
    __syncthreads();
    if (t < 160) {
        int n = t / 10, j = t % 10;
        float acc = fcb[j];
        for (int c = 0; c < 128; c++) acc += feat[n * 128 + c] * fcw[j * 128 + c];
        lg[t] = acc;
    }
    __syncthreads();
    if (t < 16) {
        float mx = -1e30f;
        for (int j = 0; j < 10; j++) mx = fmaxf(mx, lg[t * 10 + j]);
        float se = 0.f;
        for (int j = 0; j < 10; j++) se += expf(lg[t * 10 + j] - mx);
        corr[t] = mx + logf(se);
    }
    __syncthreads();
    if (t < 160) out[t] = lg[t] - corr[t / 10];
}

// -------------------------------------------------------------------- launch
#define OFF_H3P 0L
#define OFF_H2P 110592000L
#define OFF_H1P 165888000L
#define OFF_H4  110592000L
#define OFF_WF2 200507392L
#define OFF_WF3 200617984L
#define OFF_WF4 201060352L
#define OFF_STATS 201945088L

extern "C" void kernel_launch(void* const* d_in, const int* in_sizes, int n_in,
                              void* d_out, int out_size, void* d_ws, size_t ws_size,
                              hipStream_t stream) {
    const float* x       = (const float*)d_in[0];
    const float* off_w   = (const float*)d_in[1];
    const float* off_b   = (const float*)d_in[2];
    const float* dconv_w = (const float*)d_in[3];
    const float* bn1_g   = (const float*)d_in[4];
    const float* bn1_b   = (const float*)d_in[5];
    const float* conv2_w = (const float*)d_in[6];
    const float* conv2_b = (const float*)d_in[7];
    const float* bn2_g   = (const float*)d_in[8];
    const float* bn2_b   = (const float*)d_in[9];
    const float* conv3_w = (const float*)d_in[10];
    const float* conv3_b = (const float*)d_in[11];
    const float* bn3_g   = (const float*)d_in[12];
    const float* bn3_b   = (const float*)d_in[13];
    const float* conv4_w = (const float*)d_in[14];
    const float* conv4_b = (const float*)d_in[15];
    const float* bn4_g   = (const float*)d_in[16];
    const float* bn4_b   = (const float*)d_in[17];
    const float* fc_w    = (const float*)d_in[18];
    const float* fc_b    = (const float*)d_in[19];

    float* out = (float*)d_out;
    float* offsets = out + 160;

    char* ws = (char*)d_ws;
    unsigned short* h3p = (unsigned short*)(ws + OFF_H3P);
    unsigned short* h2p = (unsigned short*)(ws + OFF_H2P);
    unsigned short* h1p = (unsigned short*)(ws + OFF_H1P);
    unsigned short* h4  = (unsigned short*)(ws + OFF_H4);
    unsigned short* wf2 = (unsigned short*)(ws + OFF_WF2);
    unsigned short* wf3 = (unsigned short*)(ws + OFF_WF3);
    unsigned short* wf4 = (unsigned short*)(ws + OFF_WF4);
    float* st = (float*)(ws + OFF_STATS);
    float* sums1 = st;        float* aff1 = st + 64;
    float* sums2 = st + 128;  float* aff2 = st + 256;
    float* sums3 = st + 384;  float* aff3 = st + 640;
    float* chsq4 = st + 896;  float* pooled = st + 1024;
    float* T2 = st + 4096;    float* T3 = st + 8192;   float* T4 = st + 16384;

    hipMemsetAsync(st, 0, 3072 * sizeof(float), stream);
    hipMemsetAsync(h1p, 0, 27648000L, stream);
    hipMemsetAsync(h2p, 0, 55296000L, stream);
    hipMemsetAsync(h3p, 0, 110592000L, stream);

    k_offsets<<<dim3(1372), 256, 0, stream>>>(x, off_w, off_b, offsets);
    k_deform<<<dim3(1372), 256, 0, stream>>>(x, offsets, dconv_w, h1p);

    k_stats_p<32><<<dim3(432), 256, 0, stream>>>(h1p, sums1);
    k_finalize<<<1, 32, 0, stream>>>(sums1, bn1_g, bn1_b, aff1, 32);
    k_wfrag<32, 64><<<dim3(27), 256, 0, stream>>>(conv2_w, aff1, wf2);
    k_btab<32, 64><<<dim3(7), 256, 0, stream>>>(conv2_w, conv2_b, aff1 + 32, T2);
    k_conv_mfma<32, 64, 1, true><<<dim3(3136), 128, 0, stream>>>(h1p, wf2, T2, h2p);

    k_stats_p<64><<<dim3(432), 256, 0, stream>>>(h2p, sums2);
    k_finalize<<<1, 64, 0, stream>>>(sums2, bn2_g, bn2_b, aff2, 64);
    k_wfrag<64, 128><<<dim3(108), 256, 0, stream>>>(conv3_w, aff2, wf3);
    k_btab<64, 128><<<dim3(14), 256, 0, stream>>>(conv3_w, conv3_b, aff2 + 64, T3);
    k_conv_mfma<64, 128, 2, true><<<dim3(3136), 256, 0, stream>>>(h2p, wf3, T3, h3p);

    k_stats_p<128><<<dim3(432), 256, 0, stream>>>(h3p, sums3);
    k_finalize<<<1, 128, 0, stream>>>(sums3, bn3_g, bn3_b, aff3, 128);
    k_wfrag<128, 128><<<dim3(216), 256, 0, stream>>>(conv4_w, aff3, wf4);
    k_btab<128, 128><<<dim3(14), 256, 0, stream>>>(conv4_w, conv4_b, aff3 + 128, T4);
    k_conv_mfma<128, 128, 2, false><<<dim3(3136), 256, 0, stream>>>(h3p, wf4, T4, h4);

    k_stats4<<<dim3(16, 28), 256, 0, stream>>>(h4, pooled, chsq4);
    k_head<<<1, 256, 0, stream>>>(pooled, chsq4, bn4_g, bn4_b, fc_w, fc_b, out);
}